// Round 2
// baseline (511.773 us; speedup 1.0000x reference)
//
#include <hip/hip_runtime.h>

#define SEQ 4096
#define HID 512
#define NB  4
#define N3  1536

typedef _Float16 half_t;
typedef __attribute__((ext_vector_type(8))) _Float16 half8;
typedef __attribute__((ext_vector_type(4))) float f32x4;

#define GLOAD_LDS16(gp, lp) __builtin_amdgcn_global_load_lds((gp), (lp), 16, 0, 0)

__device__ __forceinline__ float fmax4(float4 v) {
  return fmaxf(fmaxf(v.x, v.y), fmaxf(v.z, v.w));
}

// ---------------- convert x (f32) -> f16 ----------------
__global__ void k_cvt(const float* __restrict__ x, half_t* __restrict__ xh, int n4) {
  int i = blockIdx.x * blockDim.x + threadIdx.x;
  int stride = gridDim.x * blockDim.x;
  for (; i < n4; i += stride) {
    float4 v = reinterpret_cast<const float4*>(x)[i];
    union { half_t h[4]; short4 s; } u;
    u.h[0] = (half_t)v.x; u.h[1] = (half_t)v.y;
    u.h[2] = (half_t)v.z; u.h[3] = (half_t)v.w;
    reinterpret_cast<short4*>(xh)[i] = u.s;
  }
}

// ---------------- W [512][1536] f32 -> Wt [1536][512] f16 ----------------
__global__ void k_tw(const float* __restrict__ W, half_t* __restrict__ Wt) {
  __shared__ half_t tile[64][65];
  const int n0 = blockIdx.x * 64;
  const int k0 = blockIdx.y * 64;
  const int tx = threadIdx.x & 63, ty = threadIdx.x >> 6;
#pragma unroll
  for (int i = 0; i < 64; i += 4)
    tile[ty + i][tx] = (half_t)W[(size_t)(k0 + ty + i) * N3 + n0 + tx];
  __syncthreads();
#pragma unroll
  for (int i = 0; i < 64; i += 4)
    Wt[(size_t)(n0 + ty + i) * HID + k0 + tx] = tile[tx][ty + i];
}

// ---------------- QKV projection GEMM ----------------
__launch_bounds__(256)
__global__ void k_qkv(const half_t* __restrict__ xh, const half_t* __restrict__ Wt,
                      const float* __restrict__ bias,
                      half_t* __restrict__ Qh, half_t* __restrict__ Kh,
                      half_t* __restrict__ Vt) {
  __shared__ half_t sA[128 * 32];
  __shared__ half_t sB[128 * 32];
  const int t = threadIdx.x;
  const int m0 = blockIdx.y * 128;
  const int n0 = blockIdx.x * 128;
  const int lane = t & 63, wid = t >> 6;
  const int wr = (wid >> 1) * 64, wc = (wid & 1) * 64;
  const int lrow = lane & 15, lks = lane >> 4;
  const int s1 = t, s2 = t + 256;
  const int ar1 = s1 >> 2, ac1 = (s1 & 3) * 8;
  const int ar2 = s2 >> 2, ac2 = (s2 & 3) * 8;

  f32x4 acc[4][4] = {};

  for (int k0 = 0; k0 < HID; k0 += 32) {
    __syncthreads();
    GLOAD_LDS16(xh + (size_t)(m0 + ar1) * HID + k0 + ac1, &sA[s1 * 8]);
    GLOAD_LDS16(xh + (size_t)(m0 + ar2) * HID + k0 + ac2, &sA[s2 * 8]);
    GLOAD_LDS16(Wt + (size_t)(n0 + ar1) * HID + k0 + ac1, &sB[s1 * 8]);
    GLOAD_LDS16(Wt + (size_t)(n0 + ar2) * HID + k0 + ac2, &sB[s2 * 8]);
    __syncthreads();
    half8 a[4], b[4];
#pragma unroll
    for (int m = 0; m < 4; ++m)
      a[m] = *reinterpret_cast<const half8*>(&sA[(wr + m * 16 + lrow) * 32 + lks * 8]);
#pragma unroll
    for (int n = 0; n < 4; ++n)
      b[n] = *reinterpret_cast<const half8*>(&sB[(wc + n * 16 + lrow) * 32 + lks * 8]);
#pragma unroll
    for (int m = 0; m < 4; ++m)
#pragma unroll
      for (int n = 0; n < 4; ++n)
        acc[m][n] = __builtin_amdgcn_mfma_f32_16x16x32_f16(a[m], b[n], acc[m][n], 0, 0, 0);
  }

  const float scale = 0.04419417382415922f;  // 1/sqrt(512)
  const int region = n0 >> 9;  // 0=Q, 1=K, 2=V (uniform per block)
#pragma unroll
  for (int m = 0; m < 4; ++m) {
#pragma unroll
    for (int n = 0; n < 4; ++n) {
      const int col = n0 + wc + n * 16 + lrow;
#pragma unroll
      for (int r = 0; r < 4; ++r) {
        const int row = m0 + wr + m * 16 + lks * 4 + r;
        float v = acc[m][n][r] + bias[col];
        if (region == 0) {
          Qh[(size_t)row * HID + col] = (half_t)(v * scale);
        } else if (region == 1) {
          Kh[(size_t)row * HID + (col - 512)] = (half_t)v;
        } else {
          const int bb = row >> 12, ml = row & (SEQ - 1);
          Vt[((size_t)bb * HID + (col - 1024)) * SEQ + ml] = (half_t)v;
        }
      }
    }
  }
}

// ---------------- scores = Q @ K^T, plus per-tile softmax partials ----------------
__launch_bounds__(256)
__global__ void k_qk(const half_t* __restrict__ Qh, const half_t* __restrict__ Kh,
                     float* __restrict__ S, float2* __restrict__ part) {
  __shared__ half_t sA[128 * 32];
  __shared__ half_t sB[128 * 32];
  __shared__ float lm[2][128], ls[2][128];
  const int t = threadIdx.x;
  const int bz = blockIdx.z;
  const half_t* A = Qh + (size_t)bz * SEQ * HID;
  const half_t* B = Kh + (size_t)bz * SEQ * HID;
  float* C = S + (size_t)bz * SEQ * SEQ;
  const int m0 = blockIdx.y * 128;
  const int n0 = blockIdx.x * 128;
  const int lane = t & 63, wid = t >> 6;
  const int wr = (wid >> 1) * 64, wc = (wid & 1) * 64;
  const int lrow = lane & 15, lks = lane >> 4;
  const int s1 = t, s2 = t + 256;
  const int ar1 = s1 >> 2, ac1 = (s1 & 3) * 8;
  const int ar2 = s2 >> 2, ac2 = (s2 & 3) * 8;

  f32x4 acc[4][4] = {};

  for (int k0 = 0; k0 < HID; k0 += 32) {
    __syncthreads();
    GLOAD_LDS16(A + (size_t)(m0 + ar1) * HID + k0 + ac1, &sA[s1 * 8]);
    GLOAD_LDS16(A + (size_t)(m0 + ar2) * HID + k0 + ac2, &sA[s2 * 8]);
    GLOAD_LDS16(B + (size_t)(n0 + ar1) * HID + k0 + ac1, &sB[s1 * 8]);
    GLOAD_LDS16(B + (size_t)(n0 + ar2) * HID + k0 + ac2, &sB[s2 * 8]);
    __syncthreads();
    half8 a[4], b[4];
#pragma unroll
    for (int m = 0; m < 4; ++m)
      a[m] = *reinterpret_cast<const half8*>(&sA[(wr + m * 16 + lrow) * 32 + lks * 8]);
#pragma unroll
    for (int n = 0; n < 4; ++n)
      b[n] = *reinterpret_cast<const half8*>(&sB[(wc + n * 16 + lrow) * 32 + lks * 8]);
#pragma unroll
    for (int m = 0; m < 4; ++m)
#pragma unroll
      for (int n = 0; n < 4; ++n)
        acc[m][n] = __builtin_amdgcn_mfma_f32_16x16x32_f16(a[m], b[n], acc[m][n], 0, 0, 0);
  }

  // raw score write
#pragma unroll
  for (int m = 0; m < 4; ++m)
#pragma unroll
    for (int n = 0; n < 4; ++n)
#pragma unroll
      for (int r = 0; r < 4; ++r)
        C[(size_t)(m0 + wr + m * 16 + lks * 4 + r) * SEQ + (n0 + wc + n * 16 + lrow)] =
            acc[m][n][r];

  // per-tile softmax partials: wave-local rowmax/sumexp over this wave's 64 cols
#pragma unroll
  for (int m = 0; m < 4; ++m) {
#pragma unroll
    for (int r = 0; r < 4; ++r) {
      float mx = fmaxf(fmaxf(acc[m][0][r], acc[m][1][r]),
                       fmaxf(acc[m][2][r], acc[m][3][r]));
      mx = fmaxf(mx, __shfl_xor(mx, 1));
      mx = fmaxf(mx, __shfl_xor(mx, 2));
      mx = fmaxf(mx, __shfl_xor(mx, 4));
      mx = fmaxf(mx, __shfl_xor(mx, 8));
      float s = expf(acc[m][0][r] - mx) + expf(acc[m][1][r] - mx) +
                expf(acc[m][2][r] - mx) + expf(acc[m][3][r] - mx);
      s += __shfl_xor(s, 1);
      s += __shfl_xor(s, 2);
      s += __shfl_xor(s, 4);
      s += __shfl_xor(s, 8);
      if (lrow == 0) {
        const int rr = wr + m * 16 + lks * 4 + r;
        lm[wid & 1][rr] = mx;
        ls[wid & 1][rr] = s;
      }
    }
  }
  __syncthreads();
  if (t < 128) {
    const float m0v = lm[0][t], m1v = lm[1][t];
    const float M = fmaxf(m0v, m1v);
    const float L = ls[0][t] * expf(m0v - M) + ls[1][t] * expf(m1v - M);
    part[(size_t)(bz * SEQ + m0 + t) * 32 + blockIdx.x] = make_float2(M, L);
  }
}

// ---------------- merge 32 per-tile partials per row -> (rowmax, 1/rowsum) --------
__global__ void k_lred(const float2* __restrict__ part, float2* __restrict__ stats) {
  const int row = blockIdx.x * 256 + threadIdx.x;  // [0, NB*SEQ)
  const float2* p = part + (size_t)row * 32;
  float M = -3.4028235e38f;
#pragma unroll
  for (int i = 0; i < 32; ++i) M = fmaxf(M, p[i].x);
  float L = 0.f;
#pragma unroll
  for (int i = 0; i < 32; ++i) L += p[i].y * expf(p[i].x - M);
  stats[row] = make_float2(M, 1.0f / L);
}

// ---------------- fused: normalize attn in-place + opt = attn @ V ----------------
// BM=64, BN=512 (full N): each P row read exactly once -> in-place normalize is safe.
__launch_bounds__(512, 2)
__global__ void k_pvf(float* __restrict__ P, const half_t* __restrict__ Vt,
                      const float2* __restrict__ stats, float* __restrict__ O) {
  __shared__ half_t sA[64 * 32];
  __shared__ half_t sB[512 * 32];
  const int t = threadIdx.x;
  const int bz = blockIdx.y;
  const int m0 = blockIdx.x * 64;
  float* Pb = P + (size_t)bz * SEQ * SEQ;
  const half_t* Vb = Vt + (size_t)bz * HID * SEQ;
  float* Ob = O + (size_t)bz * SEQ * HID;

  const int lane = t & 63, wid = t >> 6;
  const int wrow = (wid >> 2) * 32, wcol = (wid & 3) * 128;
  const int lrow = lane & 15, lks = lane >> 4;

  const int arow = t >> 3;       // 0..63 (fixed per thread)
  const int acol = (t & 7) * 4;  // 0..28
  const float2 st = stats[(size_t)bz * SEQ + m0 + arow];
  const float mrow = st.x, invl = st.y;

  const int brow = t >> 2;       // 0..127 (B staging base row)
  const int bcol = (t & 3) * 8;

  f32x4 acc[2][8] = {};

  for (int k0 = 0; k0 < SEQ; k0 += 32) {
    __syncthreads();
#pragma unroll
    for (int j = 0; j < 4; ++j)
      GLOAD_LDS16(Vb + (size_t)(brow + j * 128) * SEQ + k0 + bcol,
                  &sB[t * 8 + j * 4096]);
    {
      float* gp = Pb + (size_t)(m0 + arow) * SEQ + k0 + acol;
      float4 v = *reinterpret_cast<const float4*>(gp);
      v.x = expf(v.x - mrow) * invl;
      v.y = expf(v.y - mrow) * invl;
      v.z = expf(v.z - mrow) * invl;
      v.w = expf(v.w - mrow) * invl;
      *reinterpret_cast<float4*>(gp) = v;  // normalized attn, in place
      union { half_t h[4]; unsigned long long u; } cv;
      cv.h[0] = (half_t)v.x; cv.h[1] = (half_t)v.y;
      cv.h[2] = (half_t)v.z; cv.h[3] = (half_t)v.w;
      *reinterpret_cast<unsigned long long*>(&sA[arow * 32 + acol]) = cv.u;
    }
    __syncthreads();
    half8 a[2], b[8];
#pragma unroll
    for (int m = 0; m < 2; ++m)
      a[m] = *reinterpret_cast<const half8*>(&sA[(wrow + m * 16 + lrow) * 32 + lks * 8]);
#pragma unroll
    for (int n = 0; n < 8; ++n)
      b[n] = *reinterpret_cast<const half8*>(&sB[(wcol + n * 16 + lrow) * 32 + lks * 8]);
#pragma unroll
    for (int m = 0; m < 2; ++m)
#pragma unroll
      for (int n = 0; n < 8; ++n)
        acc[m][n] = __builtin_amdgcn_mfma_f32_16x16x32_f16(a[m], b[n], acc[m][n], 0, 0, 0);
  }

#pragma unroll
  for (int m = 0; m < 2; ++m)
#pragma unroll
    for (int n = 0; n < 8; ++n)
#pragma unroll
      for (int r = 0; r < 4; ++r)
        Ob[(size_t)(m0 + wrow + m * 16 + lks * 4 + r) * HID + (wcol + n * 16 + lrow)] =
            acc[m][n][r];
}

extern "C" void kernel_launch(void* const* d_in, const int* in_sizes, int n_in,
                              void* d_out, int out_size, void* d_ws, size_t ws_size,
                              hipStream_t stream) {
  const float* x = (const float*)d_in[0];     // [4,4096,512]
  const float* W = (const float*)d_in[1];     // [512,1536]
  const float* bias = (const float*)d_in[2];  // [1536]
  float* opt = (float*)d_out;                        // [4*4096*512]
  float* attn = opt + (size_t)NB * SEQ * HID;        // [4*4096*4096]

  half_t* xh = (half_t*)d_ws;                        // 16384*512
  half_t* Wt = xh + (size_t)NB * SEQ * HID;          // 1536*512
  half_t* Qh = Wt + (size_t)N3 * HID;                // 16384*512 (scale folded)
  half_t* Kh = Qh + (size_t)NB * SEQ * HID;          // 16384*512
  half_t* Vt = Kh + (size_t)NB * SEQ * HID;          // 4*[512][4096] transposed
  float2* part = (float2*)(Vt + (size_t)NB * HID * SEQ);  // [16384][32]
  float2* stats = part + (size_t)NB * SEQ * 32;           // [16384]

  k_cvt<<<2048, 256, 0, stream>>>(x, xh, NB * SEQ * HID / 4);
  k_tw<<<dim3(N3 / 64, HID / 64), 256, 0, stream>>>(W, Wt);
  k_qkv<<<dim3(N3 / 128, NB * SEQ / 128), 256, 0, stream>>>(xh, Wt, bias, Qh, Kh, Vt);
  k_qk<<<dim3(SEQ / 128, SEQ / 128, NB), 256, 0, stream>>>(Qh, Kh, attn, part);
  k_lred<<<NB * SEQ / 256, 256, 0, stream>>>(part, stats);
  k_pvf<<<dim3(SEQ / 64, NB), 512, 0, stream>>>(attn, Vt, stats, opt);
}

// Round 3
// 487.637 us; speedup vs baseline: 1.0495x; 1.0495x over previous
//
#include <hip/hip_runtime.h>

#define SEQ 4096
#define HID 512
#define NB  4
#define N3  1536

typedef _Float16 half_t;
typedef __attribute__((ext_vector_type(8))) _Float16 half8;
typedef __attribute__((ext_vector_type(4))) float f32x4;

#define GLOAD_LDS16(gp, lp) __builtin_amdgcn_global_load_lds((gp), (lp), 16, 0, 0)

__device__ __forceinline__ float fmax4(float4 v) {
  return fmaxf(fmaxf(v.x, v.y), fmaxf(v.z, v.w));
}

// ---------------- convert x (f32) -> f16 ----------------
__global__ void k_cvt(const float* __restrict__ x, half_t* __restrict__ xh, int n4) {
  int i = blockIdx.x * blockDim.x + threadIdx.x;
  int stride = gridDim.x * blockDim.x;
  for (; i < n4; i += stride) {
    float4 v = reinterpret_cast<const float4*>(x)[i];
    union { half_t h[4]; short4 s; } u;
    u.h[0] = (half_t)v.x; u.h[1] = (half_t)v.y;
    u.h[2] = (half_t)v.z; u.h[3] = (half_t)v.w;
    reinterpret_cast<short4*>(xh)[i] = u.s;
  }
}

// ---------------- W [512][1536] f32 -> Wt [1536][512] f16 ----------------
__global__ void k_tw(const float* __restrict__ W, half_t* __restrict__ Wt) {
  __shared__ half_t tile[64][65];
  const int n0 = blockIdx.x * 64;
  const int k0 = blockIdx.y * 64;
  const int tx = threadIdx.x & 63, ty = threadIdx.x >> 6;
#pragma unroll
  for (int i = 0; i < 64; i += 4)
    tile[ty + i][tx] = (half_t)W[(size_t)(k0 + ty + i) * N3 + n0 + tx];
  __syncthreads();
#pragma unroll
  for (int i = 0; i < 64; i += 4)
    Wt[(size_t)(n0 + ty + i) * HID + k0 + tx] = tile[tx][ty + i];
}

// ---------------- QKV projection GEMM ----------------
__launch_bounds__(256)
__global__ void k_qkv(const half_t* __restrict__ xh, const half_t* __restrict__ Wt,
                      const float* __restrict__ bias,
                      half_t* __restrict__ Qh, half_t* __restrict__ Kh,
                      half_t* __restrict__ Vt) {
  __shared__ half_t sA[128 * 32];
  __shared__ half_t sB[128 * 32];
  const int t = threadIdx.x;
  const int m0 = blockIdx.y * 128;
  const int n0 = blockIdx.x * 128;
  const int lane = t & 63, wid = t >> 6;
  const int wr = (wid >> 1) * 64, wc = (wid & 1) * 64;
  const int lrow = lane & 15, lks = lane >> 4;
  const int s1 = t, s2 = t + 256;
  const int ar1 = s1 >> 2, ac1 = (s1 & 3) * 8;
  const int ar2 = s2 >> 2, ac2 = (s2 & 3) * 8;

  f32x4 acc[4][4] = {};

  for (int k0 = 0; k0 < HID; k0 += 32) {
    __syncthreads();
    GLOAD_LDS16(xh + (size_t)(m0 + ar1) * HID + k0 + ac1, &sA[s1 * 8]);
    GLOAD_LDS16(xh + (size_t)(m0 + ar2) * HID + k0 + ac2, &sA[s2 * 8]);
    GLOAD_LDS16(Wt + (size_t)(n0 + ar1) * HID + k0 + ac1, &sB[s1 * 8]);
    GLOAD_LDS16(Wt + (size_t)(n0 + ar2) * HID + k0 + ac2, &sB[s2 * 8]);
    __syncthreads();
    half8 a[4], b[4];
#pragma unroll
    for (int m = 0; m < 4; ++m)
      a[m] = *reinterpret_cast<const half8*>(&sA[(wr + m * 16 + lrow) * 32 + lks * 8]);
#pragma unroll
    for (int n = 0; n < 4; ++n)
      b[n] = *reinterpret_cast<const half8*>(&sB[(wc + n * 16 + lrow) * 32 + lks * 8]);
#pragma unroll
    for (int m = 0; m < 4; ++m)
#pragma unroll
      for (int n = 0; n < 4; ++n)
        acc[m][n] = __builtin_amdgcn_mfma_f32_16x16x32_f16(a[m], b[n], acc[m][n], 0, 0, 0);
  }

  const float scale = 0.04419417382415922f;  // 1/sqrt(512)
  const int region = n0 >> 9;  // 0=Q, 1=K, 2=V (uniform per block)
#pragma unroll
  for (int m = 0; m < 4; ++m) {
#pragma unroll
    for (int n = 0; n < 4; ++n) {
      const int col = n0 + wc + n * 16 + lrow;
#pragma unroll
      for (int r = 0; r < 4; ++r) {
        const int row = m0 + wr + m * 16 + lks * 4 + r;
        float v = acc[m][n][r] + bias[col];
        if (region == 0) {
          Qh[(size_t)row * HID + col] = (half_t)(v * scale);
        } else if (region == 1) {
          Kh[(size_t)row * HID + (col - 512)] = (half_t)v;
        } else {
          const int bb = row >> 12, ml = row & (SEQ - 1);
          Vt[((size_t)bb * HID + (col - 1024)) * SEQ + ml] = (half_t)v;
        }
      }
    }
  }
}

// ---------------- scores = Q @ K^T, plus per-tile softmax partials ----------------
__launch_bounds__(256)
__global__ void k_qk(const half_t* __restrict__ Qh, const half_t* __restrict__ Kh,
                     float* __restrict__ S, float2* __restrict__ part) {
  __shared__ half_t sA[128 * 32];
  __shared__ half_t sB[128 * 32];
  __shared__ float lm[2][128], ls[2][128];
  const int t = threadIdx.x;
  const int bz = blockIdx.z;
  const half_t* A = Qh + (size_t)bz * SEQ * HID;
  const half_t* B = Kh + (size_t)bz * SEQ * HID;
  float* C = S + (size_t)bz * SEQ * SEQ;
  const int m0 = blockIdx.y * 128;
  const int n0 = blockIdx.x * 128;
  const int lane = t & 63, wid = t >> 6;
  const int wr = (wid >> 1) * 64, wc = (wid & 1) * 64;
  const int lrow = lane & 15, lks = lane >> 4;
  const int s1 = t, s2 = t + 256;
  const int ar1 = s1 >> 2, ac1 = (s1 & 3) * 8;
  const int ar2 = s2 >> 2, ac2 = (s2 & 3) * 8;

  f32x4 acc[4][4] = {};

  for (int k0 = 0; k0 < HID; k0 += 32) {
    __syncthreads();
    GLOAD_LDS16(A + (size_t)(m0 + ar1) * HID + k0 + ac1, &sA[s1 * 8]);
    GLOAD_LDS16(A + (size_t)(m0 + ar2) * HID + k0 + ac2, &sA[s2 * 8]);
    GLOAD_LDS16(B + (size_t)(n0 + ar1) * HID + k0 + ac1, &sB[s1 * 8]);
    GLOAD_LDS16(B + (size_t)(n0 + ar2) * HID + k0 + ac2, &sB[s2 * 8]);
    __syncthreads();
    half8 a[4], b[4];
#pragma unroll
    for (int m = 0; m < 4; ++m)
      a[m] = *reinterpret_cast<const half8*>(&sA[(wr + m * 16 + lrow) * 32 + lks * 8]);
#pragma unroll
    for (int n = 0; n < 4; ++n)
      b[n] = *reinterpret_cast<const half8*>(&sB[(wc + n * 16 + lrow) * 32 + lks * 8]);
#pragma unroll
    for (int m = 0; m < 4; ++m)
#pragma unroll
      for (int n = 0; n < 4; ++n)
        acc[m][n] = __builtin_amdgcn_mfma_f32_16x16x32_f16(a[m], b[n], acc[m][n], 0, 0, 0);
  }

  // raw score write
#pragma unroll
  for (int m = 0; m < 4; ++m)
#pragma unroll
    for (int n = 0; n < 4; ++n)
#pragma unroll
      for (int r = 0; r < 4; ++r)
        C[(size_t)(m0 + wr + m * 16 + lks * 4 + r) * SEQ + (n0 + wc + n * 16 + lrow)] =
            acc[m][n][r];

  // per-tile softmax partials
#pragma unroll
  for (int m = 0; m < 4; ++m) {
#pragma unroll
    for (int r = 0; r < 4; ++r) {
      float mx = fmaxf(fmaxf(acc[m][0][r], acc[m][1][r]),
                       fmaxf(acc[m][2][r], acc[m][3][r]));
      mx = fmaxf(mx, __shfl_xor(mx, 1));
      mx = fmaxf(mx, __shfl_xor(mx, 2));
      mx = fmaxf(mx, __shfl_xor(mx, 4));
      mx = fmaxf(mx, __shfl_xor(mx, 8));
      float s = expf(acc[m][0][r] - mx) + expf(acc[m][1][r] - mx) +
                expf(acc[m][2][r] - mx) + expf(acc[m][3][r] - mx);
      s += __shfl_xor(s, 1);
      s += __shfl_xor(s, 2);
      s += __shfl_xor(s, 4);
      s += __shfl_xor(s, 8);
      if (lrow == 0) {
        const int rr = wr + m * 16 + lks * 4 + r;
        lm[wid & 1][rr] = mx;
        ls[wid & 1][rr] = s;
      }
    }
  }
  __syncthreads();
  if (t < 128) {
    const float m0v = lm[0][t], m1v = lm[1][t];
    const float M = fmaxf(m0v, m1v);
    const float L = ls[0][t] * expf(m0v - M) + ls[1][t] * expf(m1v - M);
    part[(size_t)(bz * SEQ + m0 + t) * 32 + blockIdx.x] = make_float2(M, L);
  }
}

// ---------------- merge 32 per-tile partials per row -> (rowmax, 1/rowsum) --------
__global__ void k_lred(const float2* __restrict__ part, float2* __restrict__ stats) {
  const int row = blockIdx.x * 256 + threadIdx.x;  // [0, NB*SEQ)
  const float2* p = part + (size_t)row * 32;
  float M = -3.4028235e38f;
#pragma unroll
  for (int i = 0; i < 32; ++i) M = fmaxf(M, p[i].x);
  float L = 0.f;
#pragma unroll
  for (int i = 0; i < 32; ++i) L += p[i].y * expf(p[i].x - M);
  stats[row] = make_float2(M, 1.0f / L);
}

// ---------------- fused: normalize attn in-place + opt = attn @ V ----------------
// BM=32, BN=512 (full N), BK=64. Grid 512 blocks -> 2 blocks/CU. XOR-swizzled LDS.
__launch_bounds__(512, 4)
__global__ void k_pvn(float* __restrict__ P, const half_t* __restrict__ Vt,
                      const float2* __restrict__ stats, float* __restrict__ O) {
  __shared__ half_t sA[32 * 64];    // 4 KB, XOR-swizzled
  __shared__ half_t sB[512 * 64];   // 64 KB, XOR-swizzled via pre-swizzled source
  const int t = threadIdx.x;

  // bijective XCD swizzle: 512 blocks, 64 per XCD -> each XCD works one V panel
  const int bid = blockIdx.x;
  const int sw = (bid & 7) * 64 + (bid >> 3);
  const int bz = sw >> 7;
  const int m0 = (sw & 127) * 32;

  float* Pb = P + (size_t)bz * SEQ * SEQ;
  const half_t* Vb = Vt + (size_t)bz * HID * SEQ;
  float* Ob = O + (size_t)bz * SEQ * HID;

  const int lane = t & 63, wid = t >> 6;
  const int lrow = lane & 15, lks = lane >> 4;

  // A staging: 32x64 f32 raw scores -> exp -> attn(in place) -> f16 LDS
  const int arow = t >> 4;         // 0..31
  const int acol = (t & 15) * 4;   // 0..60
  const float2 st = stats[(size_t)bz * SEQ + m0 + arow];
  const float mrow = st.x, invl = st.y;
  const int aswz = arow * 64 + (acol ^ ((arow & 7) << 3));

  // B staging via global_load_lds: linear dest + inverse-swizzled source
  const int brow = t >> 3;                                  // 0..63 (+ j*64)
  const int bslot = ((t & 7) ^ ((t >> 3) & 7)) << 3;        // swizzled col (halves)

  f32x4 acc[2][4] = {};

  for (int k0 = 0; k0 < SEQ; k0 += 64) {
    __syncthreads();
#pragma unroll
    for (int j = 0; j < 8; ++j)
      GLOAD_LDS16(Vb + (size_t)(brow + j * 64) * SEQ + k0 + bslot,
                  &sB[t * 8 + j * 4096]);
    {
      float* gp = Pb + (size_t)(m0 + arow) * SEQ + k0 + acol;
      float4 v = *reinterpret_cast<const float4*>(gp);
      v.x = expf(v.x - mrow) * invl;
      v.y = expf(v.y - mrow) * invl;
      v.z = expf(v.z - mrow) * invl;
      v.w = expf(v.w - mrow) * invl;
      *reinterpret_cast<float4*>(gp) = v;  // normalized attn, in place
      union { half_t h[4]; unsigned long long u; } cv;
      cv.h[0] = (half_t)v.x; cv.h[1] = (half_t)v.y;
      cv.h[2] = (half_t)v.z; cv.h[3] = (half_t)v.w;
      *reinterpret_cast<unsigned long long*>(&sA[aswz]) = cv.u;
    }
    __syncthreads();
#pragma unroll
    for (int kk = 0; kk < 2; ++kk) {
      half8 a[2], b[4];
#pragma unroll
      for (int m = 0; m < 2; ++m) {
        const int row = m * 16 + lrow;
        a[m] = *reinterpret_cast<const half8*>(
            &sA[row * 64 + ((kk * 32 + lks * 8) ^ ((row & 7) << 3))]);
      }
#pragma unroll
      for (int n = 0; n < 4; ++n) {
        const int row = wid * 64 + n * 16 + lrow;
        b[n] = *reinterpret_cast<const half8*>(
            &sB[row * 64 + ((kk * 32 + lks * 8) ^ ((row & 7) << 3))]);
      }
#pragma unroll
      for (int m = 0; m < 2; ++m)
#pragma unroll
        for (int n = 0; n < 4; ++n)
          acc[m][n] = __builtin_amdgcn_mfma_f32_16x16x32_f16(a[m], b[n], acc[m][n], 0, 0, 0);
    }
  }

#pragma unroll
  for (int m = 0; m < 2; ++m)
#pragma unroll
    for (int n = 0; n < 4; ++n)
#pragma unroll
      for (int r = 0; r < 4; ++r)
        Ob[(size_t)(m0 + m * 16 + lks * 4 + r) * HID + (wid * 64 + n * 16 + lrow)] =
            acc[m][n][r];
}

extern "C" void kernel_launch(void* const* d_in, const int* in_sizes, int n_in,
                              void* d_out, int out_size, void* d_ws, size_t ws_size,
                              hipStream_t stream) {
  const float* x = (const float*)d_in[0];     // [4,4096,512]
  const float* W = (const float*)d_in[1];     // [512,1536]
  const float* bias = (const float*)d_in[2];  // [1536]
  float* opt = (float*)d_out;                        // [4*4096*512]
  float* attn = opt + (size_t)NB * SEQ * HID;        // [4*4096*4096]

  half_t* xh = (half_t*)d_ws;                        // 16384*512
  half_t* Wt = xh + (size_t)NB * SEQ * HID;          // 1536*512
  half_t* Qh = Wt + (size_t)N3 * HID;                // 16384*512 (scale folded)
  half_t* Kh = Qh + (size_t)NB * SEQ * HID;          // 16384*512
  half_t* Vt = Kh + (size_t)NB * SEQ * HID;          // 4*[512][4096] transposed
  float2* part = (float2*)(Vt + (size_t)NB * HID * SEQ);  // [16384][32]
  float2* stats = part + (size_t)NB * SEQ * 32;           // [16384]

  k_cvt<<<2048, 256, 0, stream>>>(x, xh, NB * SEQ * HID / 4);
  k_tw<<<dim3(N3 / 64, HID / 64), 256, 0, stream>>>(W, Wt);
  k_qkv<<<dim3(N3 / 128, NB * SEQ / 128), 256, 0, stream>>>(xh, Wt, bias, Qh, Kh, Vt);
  k_qk<<<dim3(SEQ / 128, SEQ / 128, NB), 256, 0, stream>>>(Qh, Kh, attn, part);
  k_lred<<<NB * SEQ / 256, 256, 0, stream>>>(part, stats);
  k_pvn<<<512, 512, 0, stream>>>(attn, Vt, stats, opt);
}